// Round 1
// baseline (2347.757 us; speedup 1.0000x reference)
//
#include <hip/hip_runtime.h>
#include <cmath>

#define BM   128   // rows per block
#define NH   128   // hidden chunk width
#define BK   32    // K slice
#define NE   16
#define DIN  256
#define DHID 512

__global__ __launch_bounds__(256, 2)
void moe_router(const float* __restrict__ x,
                const float* __restrict__ w1,
                const float* __restrict__ b1,
                const float* __restrict__ w2,
                const float* __restrict__ b2,
                float* __restrict__ out)
{
    __shared__ float x_sl[BK][BM + 4];   // transposed: x_sl[k][row]
    __shared__ float w_sl[BK][NH + 4];   // w_sl[k][col]
    __shared__ float l_lds[BM][NE + 1];

    const int t  = threadIdx.x;
    const int tc = t & 15;    // column group (also: expert owned by this lane)
    const int tr = t >> 4;    // row group (rows tr*8 .. tr*8+7)
    const long long row0 = (long long)blockIdx.x * BM;

    float logits[8];
#pragma unroll
    for (int i = 0; i < 8; ++i) logits[i] = 0.f;

    for (int ch = 0; ch < DHID / NH; ++ch) {
        const int nh0 = ch * NH;
        float acc[8][8];
#pragma unroll
        for (int i = 0; i < 8; ++i)
#pragma unroll
            for (int j = 0; j < 8; ++j) acc[i][j] = 0.f;

        for (int ks = 0; ks < DIN / BK; ++ks) {
            const int k0 = ks * BK;

            // ---- stage x slice (transposed into LDS) ----
            {
                const int r    = t & 127;
                const int half = t >> 7;   // 0..1
                const float* xg = x + (row0 + r) * DIN + k0 + half * 16;
#pragma unroll
                for (int u = 0; u < 4; ++u) {
                    float4 v = ((const float4*)xg)[u];
                    const int kk = half * 16 + u * 4;
                    x_sl[kk + 0][r] = v.x;
                    x_sl[kk + 1][r] = v.y;
                    x_sl[kk + 2][r] = v.z;
                    x_sl[kk + 3][r] = v.w;
                }
            }
            // ---- stage w1 slice ----
            {
                const int wk  = t >> 3;    // 0..31
                const int seg = t & 7;     // 0..7 (16 floats each)
                const float* wg = w1 + (long long)(k0 + wk) * DHID + nh0 + seg * 16;
#pragma unroll
                for (int u = 0; u < 4; ++u) {
                    float4 v = ((const float4*)wg)[u];
                    *(float4*)&w_sl[wk][seg * 16 + u * 4] = v;
                }
            }
            __syncthreads();

            // ---- 128x128x32 fp32 register-tile GEMM step ----
#pragma unroll 4
            for (int k = 0; k < BK; ++k) {
                float4 xa = *(const float4*)&x_sl[k][tr * 8];
                float4 xb = *(const float4*)&x_sl[k][tr * 8 + 4];
                float4 wa = *(const float4*)&w_sl[k][tc * 4];
                float4 wb = *(const float4*)&w_sl[k][64 + tc * 4];
                float xr[8] = {xa.x, xa.y, xa.z, xa.w, xb.x, xb.y, xb.z, xb.w};
                float wc[8] = {wa.x, wa.y, wa.z, wa.w, wb.x, wb.y, wb.z, wb.w};
#pragma unroll
                for (int i = 0; i < 8; ++i)
#pragma unroll
                    for (int j = 0; j < 8; ++j)
                        acc[i][j] = fmaf(xr[i], wc[j], acc[i][j]);
            }
            __syncthreads();
        }

        // ---- bias + relu (h lives in acc) ----
#pragma unroll
        for (int j = 0; j < 8; ++j) {
            const int cj = tc * 4 + (j & 3) + ((j >> 2) << 6);
            const float bj = b1[nh0 + cj];
#pragma unroll
            for (int i = 0; i < 8; ++i)
                acc[i][j] = fmaxf(acc[i][j] + bj, 0.f);
        }

        // ---- fused layer 2: logits[r][e] += sum_c h[r][c]*w2[c][e] ----
#pragma unroll 1
        for (int e = 0; e < NE; ++e) {
            float p[8];
#pragma unroll
            for (int i = 0; i < 8; ++i) p[i] = 0.f;
#pragma unroll
            for (int j = 0; j < 8; ++j) {
                const int cj = tc * 4 + (j & 3) + ((j >> 2) << 6);
                const float wv = w2[(nh0 + cj) * NE + e];
#pragma unroll
                for (int i = 0; i < 8; ++i) p[i] = fmaf(acc[i][j], wv, p[i]);
            }
            // butterfly-reduce across the 16 tc-lanes (within wave)
#pragma unroll
            for (int m = 1; m < 16; m <<= 1)
#pragma unroll
                for (int i = 0; i < 8; ++i)
                    p[i] += __shfl_xor(p[i], m, 64);
            if (tc == e) {
#pragma unroll
                for (int i = 0; i < 8; ++i) logits[i] += p[i];
            }
        }
    }

    // ---- gather logits to LDS (this lane owns expert tc) ----
    const float be = b2[tc];
#pragma unroll
    for (int i = 0; i < 8; ++i)
        l_lds[tr * 8 + i][tc] = logits[i] + be;
    __syncthreads();

    // ---- per-row top-2 + masked softmax ----
    if (t < BM) {
        float l[NE];
#pragma unroll
        for (int e = 0; e < NE; ++e) l[e] = l_lds[t][e];

        float m1 = -INFINITY; int i1 = 0;
#pragma unroll
        for (int e = 0; e < NE; ++e)
            if (l[e] > m1) { m1 = l[e]; i1 = e; }
        float m2 = -INFINITY; int i2 = -1;
#pragma unroll
        for (int e = 0; e < NE; ++e)
            if (e != i1 && l[e] > m2) { m2 = l[e]; i2 = e; }

        float s[NE];
#pragma unroll
        for (int e = 0; e < NE; ++e)
            s[e] = (e == i1 || e == i2) ? l[e] : 0.f;

        float mx = s[0];
#pragma unroll
        for (int e = 1; e < NE; ++e) mx = fmaxf(mx, s[e]);

        float ex[NE];
        float sum = 0.f;
#pragma unroll
        for (int e = 0; e < NE; ++e) { ex[e] = expf(s[e] - mx); sum += ex[e]; }

        float* og = out + (row0 + t) * NE;
#pragma unroll
        for (int e = 0; e < NE; ++e) og[e] = ex[e] / sum;
    }
}

extern "C" void kernel_launch(void* const* d_in, const int* in_sizes, int n_in,
                              void* d_out, int out_size, void* d_ws, size_t ws_size,
                              hipStream_t stream) {
    const float* x  = (const float*)d_in[0];
    const float* w1 = (const float*)d_in[1];
    const float* b1 = (const float*)d_in[2];
    const float* w2 = (const float*)d_in[3];
    const float* b2 = (const float*)d_in[4];
    float* outp = (float*)d_out;

    dim3 grid(524288 / BM);
    dim3 block(256);
    hipLaunchKernelGGL(moe_router, grid, block, 0, stream,
                       x, w1, b1, w2, b2, outp);
}

// Round 2
// 2006.053 us; speedup vs baseline: 1.1703x; 1.1703x over previous
//
#include <hip/hip_runtime.h>
#include <cmath>

#define BM   256   // rows per block
#define NH   128   // hidden chunk width
#define BK   32    // K slice
#define NE   16
#define DIN  256
#define DHID 512
#define XSTR 260   // x_sl row stride in floats (pad 4)
#define WSTR 132   // w_sl row stride in floats (pad 4)

template<int CTRL>
__device__ __forceinline__ float dpp_xor_add(float v) {
    // v + v(lane ^ m) via quad_perm DPP (VALU pipe, bit-identical to shfl_xor)
    int s = __builtin_amdgcn_update_dpp(0, __float_as_int(v), CTRL, 0xF, 0xF, true);
    return v + __int_as_float(s);
}
template<int OFF>
__device__ __forceinline__ float swz_xor_add(float v) {
    int s = __builtin_amdgcn_ds_swizzle(__float_as_int(v), OFF);
    return v + __int_as_float(s);
}

__global__ __launch_bounds__(256, 2)
void moe_router(const float* __restrict__ x,
                const float* __restrict__ w1,
                const float* __restrict__ b1,
                const float* __restrict__ w2,
                const float* __restrict__ b2,
                float* __restrict__ out)
{
    __shared__ __align__(16) float smem[BK * XSTR + BK * WSTR];
    float* x_sl  = smem;               // [BK][XSTR]  (transposed: x_sl[k][row])
    float* w_sl  = smem + BK * XSTR;   // [BK][WSTR]  (w_sl[k][col])
    float* l_lds = smem;               // [BM][NE+1]  overlay (after main loop)

    const int t  = threadIdx.x;
    const int tc = t & 15;    // column group / owned expert
    const int tr = t >> 4;    // row group (rows tr*16 .. tr*16+15)
    const long long row0 = (long long)blockIdx.x * BM;

    float logits[16];
#pragma unroll
    for (int i = 0; i < 16; ++i) logits[i] = 0.f;

    for (int ch = 0; ch < DHID / NH; ++ch) {
        const int nh0 = ch * NH;
        float acc[16][8];
#pragma unroll
        for (int i = 0; i < 16; ++i)
#pragma unroll
            for (int j = 0; j < 8; ++j) acc[i][j] = 0.f;

        for (int ks = 0; ks < DIN / BK; ++ks) {
            const int k0 = ks * BK;

            // ---- stage x slice (transposed): thread t owns row t, 32 k's ----
            {
                const float* xg = x + (row0 + t) * DIN + k0;
#pragma unroll
                for (int u = 0; u < 8; ++u) {
                    float4 v = ((const float4*)xg)[u];
                    const int kk = u * 4;
                    x_sl[(kk + 0) * XSTR + t] = v.x;
                    x_sl[(kk + 1) * XSTR + t] = v.y;
                    x_sl[(kk + 2) * XSTR + t] = v.z;
                    x_sl[(kk + 3) * XSTR + t] = v.w;
                }
            }
            // ---- stage w1 slice: thread t owns (row t>>3, 16-float seg t&7) ----
            {
                const int wk = t >> 3;          // 0..31
                const int sb = (t & 7) * 16;    // 0,16,...,112
                const float* wg = w1 + (long long)(k0 + wk) * DHID + nh0 + sb;
#pragma unroll
                for (int u = 0; u < 4; ++u) {
                    float4 v = ((const float4*)wg)[u];
                    *(float4*)&w_sl[wk * WSTR + sb + u * 4] = v;
                }
            }
            __syncthreads();

            // ---- 256x128x32 fp32 register-tile step: 16x8 per thread ----
#pragma unroll 4
            for (int k = 0; k < BK; ++k) {
                float4 xa = *(const float4*)&x_sl[k * XSTR + tr * 16];
                float4 xb = *(const float4*)&x_sl[k * XSTR + tr * 16 + 4];
                float4 xc = *(const float4*)&x_sl[k * XSTR + tr * 16 + 8];
                float4 xd = *(const float4*)&x_sl[k * XSTR + tr * 16 + 12];
                float4 wa = *(const float4*)&w_sl[k * WSTR + tc * 4];
                float4 wb = *(const float4*)&w_sl[k * WSTR + 64 + tc * 4];
                float xr[16] = {xa.x, xa.y, xa.z, xa.w, xb.x, xb.y, xb.z, xb.w,
                                xc.x, xc.y, xc.z, xc.w, xd.x, xd.y, xd.z, xd.w};
                float wc[8]  = {wa.x, wa.y, wa.z, wa.w, wb.x, wb.y, wb.z, wb.w};
#pragma unroll
                for (int i = 0; i < 16; ++i)
#pragma unroll
                    for (int j = 0; j < 8; ++j)
                        acc[i][j] = fmaf(xr[i], wc[j], acc[i][j]);
            }
            __syncthreads();
        }

        // ---- bias + relu ----
#pragma unroll
        for (int j = 0; j < 8; ++j) {
            const int cj = tc * 4 + (j & 3) + ((j >> 2) << 6);
            const float bj = b1[nh0 + cj];
#pragma unroll
            for (int i = 0; i < 16; ++i)
                acc[i][j] = fmaxf(acc[i][j] + bj, 0.f);
        }

        // ---- fused layer 2 (register-only; butterfly via DPP + ds_swizzle) ----
#pragma unroll 1
        for (int e = 0; e < NE; ++e) {
            float p[16];
#pragma unroll
            for (int i = 0; i < 16; ++i) p[i] = 0.f;
#pragma unroll
            for (int j = 0; j < 8; ++j) {
                const int cj = tc * 4 + (j & 3) + ((j >> 2) << 6);
                const float wv = w2[(nh0 + cj) * NE + e];
#pragma unroll
                for (int i = 0; i < 16; ++i) p[i] = fmaf(acc[i][j], wv, p[i]);
            }
            // xor-1 quad_perm(1,0,3,2)=0xB1 ; xor-2 quad_perm(2,3,0,1)=0x4E
#pragma unroll
            for (int i = 0; i < 16; ++i) p[i] = dpp_xor_add<0xB1>(p[i]);
#pragma unroll
            for (int i = 0; i < 16; ++i) p[i] = dpp_xor_add<0x4E>(p[i]);
            // xor-4 = 0x101F, xor-8 = 0x201F (BitMode: (xor<<10)|0x1F)
#pragma unroll
            for (int i = 0; i < 16; ++i) p[i] = swz_xor_add<0x101F>(p[i]);
#pragma unroll
            for (int i = 0; i < 16; ++i) p[i] = swz_xor_add<0x201F>(p[i]);
            if (tc == e) {
#pragma unroll
                for (int i = 0; i < 16; ++i) logits[i] += p[i];
            }
        }
    }

    // ---- gather logits to LDS (overlay region; prior sync guarantees safety) ----
    const float be = b2[tc];
#pragma unroll
    for (int i = 0; i < 16; ++i)
        l_lds[(tr * 16 + i) * (NE + 1) + tc] = logits[i] + be;
    __syncthreads();

    // ---- per-row top-2 + masked softmax (1 thread per row) ----
    {
        float l[NE];
#pragma unroll
        for (int e = 0; e < NE; ++e) l[e] = l_lds[t * (NE + 1) + e];

        float m1 = -INFINITY; int i1 = 0;
#pragma unroll
        for (int e = 0; e < NE; ++e)
            if (l[e] > m1) { m1 = l[e]; i1 = e; }
        float m2 = -INFINITY; int i2 = -1;
#pragma unroll
        for (int e = 0; e < NE; ++e)
            if (e != i1 && l[e] > m2) { m2 = l[e]; i2 = e; }

        float s[NE];
#pragma unroll
        for (int e = 0; e < NE; ++e)
            s[e] = (e == i1 || e == i2) ? l[e] : 0.f;

        float mx = s[0];
#pragma unroll
        for (int e = 1; e < NE; ++e) mx = fmaxf(mx, s[e]);

        float ex[NE];
        float sum = 0.f;
#pragma unroll
        for (int e = 0; e < NE; ++e) { ex[e] = expf(s[e] - mx); sum += ex[e]; }

        float* og = out + (row0 + t) * NE;
#pragma unroll
        for (int e = 0; e < NE; ++e) og[e] = ex[e] / sum;
    }
}

extern "C" void kernel_launch(void* const* d_in, const int* in_sizes, int n_in,
                              void* d_out, int out_size, void* d_ws, size_t ws_size,
                              hipStream_t stream) {
    const float* x  = (const float*)d_in[0];
    const float* w1 = (const float*)d_in[1];
    const float* b1 = (const float*)d_in[2];
    const float* w2 = (const float*)d_in[3];
    const float* b2 = (const float*)d_in[4];
    float* outp = (float*)d_out;

    dim3 grid(524288 / BM);
    dim3 block(256);
    hipLaunchKernelGGL(moe_router, grid, block, 0, stream,
                       x, w1, b1, w2, b2, outp);
}